// Round 4
// baseline (54.313 us; speedup 1.0000x reference)
//
#include <hip/hip_runtime.h>
#include <math.h>

#define D_DIM 128
#define M_CLUSTERS 64
#define ROWS 128          // rows per block (4 waves x 32 rows)
#define BLOCK 256
#define RBLOCK 256

typedef __bf16 bf16x8 __attribute__((ext_vector_type(8)));
typedef float f32x4 __attribute__((ext_vector_type(4)));

union B8 {
    int4 i;
    bf16x8 b;
    unsigned int u[4];
};

__device__ __forceinline__ unsigned int pack_bf16(float a, float b) {
    unsigned int ua = __float_as_uint(a), ub = __float_as_uint(b);
    ua = (ua + 0x7FFFu + ((ua >> 16) & 1u)) >> 16;   // RN-even
    ub = (ub + 0x7FFFu + ((ub >> 16) & 1u)) >> 16;
    return ua | (ub << 16);
}

__device__ __forceinline__ float zval(float sq) {
    float dd = sqrtf(fmaxf(sq, 0.0f));
    float sg = __fdividef(1.0f, 1.0f + __expf(dd));
    return -__logf(sg + 1e-8f);
}

// Prep: muB4 = bf16(mus) linear [64 clusters][16 slots of 16B]; m2 = ||mu||^2 f32.
__global__ void iso_prep(const float4* __restrict__ mus4, int4* __restrict__ muB4,
                         float* __restrict__ m2) {
    const int t = threadIdx.x;
#pragma unroll
    for (int i = 0; i < 4; ++i) {
        int f = i * 256 + t;               // 1024 chunks of 8 f32
        float4 v0 = mus4[f * 2 + 0];
        float4 v1 = mus4[f * 2 + 1];
        int4 p;
        p.x = (int)pack_bf16(v0.x, v0.y);
        p.y = (int)pack_bf16(v0.z, v0.w);
        p.z = (int)pack_bf16(v1.x, v1.y);
        p.w = (int)pack_bf16(v1.z, v1.w);
        muB4[f] = p;
    }
    if (t < M_CLUSTERS) {
        const float4* mv = mus4 + t * (D_DIM / 4);
        float s = 0.f;
#pragma unroll
        for (int d = 0; d < D_DIM / 4; ++d) {
            float4 v = mv[d];
            s = fmaf(v.x, v.x, s);
            s = fmaf(v.y, v.y, s);
            s = fmaf(v.z, v.z, s);
            s = fmaf(v.w, v.w, s);
        }
        m2[t] = s;
    }
}

// Main: no tile LDS. A-fragments straight from global X (f32 -> bf16 in reg),
// B-fragments straight from muB4 (16KB, L1-resident). Fused epilogue.
__global__ __launch_bounds__(BLOCK) void iso_main(
        const float4* __restrict__ X4, const float* __restrict__ r,
        const int4* __restrict__ muB4, const float* __restrict__ m2g,
        float* __restrict__ partials, int N) {
    __shared__ float pl[BLOCK];

    const int tid = threadIdx.x;
    const int lane = tid & 63;
    const int w = tid >> 6;
    const int la = lane & 15;
    const int lg = lane >> 4;
    const int rowbase = blockIdx.x * ROWS + w * 32;   // wave-exclusive 32 rows

    f32x4 acc[2][4];
#pragma unroll
    for (int ra = 0; ra < 2; ++ra)
#pragma unroll
        for (int cb = 0; cb < 4; ++cb)
#pragma unroll
            for (int q = 0; q < 4; ++q) acc[ra][cb][q] = 0.f;
    float x2p[2] = {0.f, 0.f};

#pragma unroll
    for (int kk = 0; kk < 4; ++kk) {
        // A: lane (la,lg) needs X[rowbase+ra*16+la][kk*32+lg*8 .. +8] (f32).
        // Per instr: 16 rows x 128 contiguous bytes -> fully coalesced lines.
        B8 a[2];
#pragma unroll
        for (int ra = 0; ra < 2; ++ra) {
            int row = rowbase + ra * 16 + la;
            float4 v0 = make_float4(0.f, 0.f, 0.f, 0.f), v1 = v0;
            if (row < N) {
                const float4* p = X4 + (size_t)row * 32 + kk * 8 + lg * 2;
                v0 = p[0];
                v1 = p[1];
            }
            a[ra].u[0] = pack_bf16(v0.x, v0.y);
            a[ra].u[1] = pack_bf16(v0.z, v0.w);
            a[ra].u[2] = pack_bf16(v1.x, v1.y);
            a[ra].u[3] = pack_bf16(v1.z, v1.w);
        }
        // B: cluster cb*16+la, slot kk*4+lg (layout proven in round 3).
        B8 b[4];
#pragma unroll
        for (int cb = 0; cb < 4; ++cb)
            b[cb].i = muB4[(cb * 16 + la) * 16 + kk * 4 + lg];
#pragma unroll
        for (int ra = 0; ra < 2; ++ra)
#pragma unroll
            for (int cb = 0; cb < 4; ++cb)
                acc[ra][cb] = __builtin_amdgcn_mfma_f32_16x16x32_bf16(
                    a[ra].b, b[cb].b, acc[ra][cb], 0, 0, 0);
        // x2 from same bf16 values (exact widen via bit ops).
#pragma unroll
        for (int ra = 0; ra < 2; ++ra)
#pragma unroll
            for (int j = 0; j < 4; ++j) {
                unsigned int u = a[ra].u[j];
                float f0 = __uint_as_float(u << 16);
                float f1 = __uint_as_float(u & 0xFFFF0000u);
                x2p[ra] = fmaf(f0, f0, fmaf(f1, f1, x2p[ra]));
            }
    }

    // x2: lane (la,lg) holds quarter-sums of row la -> reduce over lg.
#pragma unroll
    for (int ra = 0; ra < 2; ++ra) {
        x2p[ra] += __shfl_xor(x2p[ra], 16, 64);
        x2p[ra] += __shfl_xor(x2p[ra], 32, 64);
    }

    // Epilogue. C/D layout: col = la, row = lg*4 + q (m89-verified).
    float m2r[4];
#pragma unroll
    for (int cb = 0; cb < 4; ++cb) m2r[cb] = m2g[cb * 16 + la];

    float rv[2][4][4];
    float x2r[2][4];
#pragma unroll
    for (int ra = 0; ra < 2; ++ra)
#pragma unroll
        for (int q = 0; q < 4; ++q) {
            x2r[ra][q] = __shfl(x2p[ra], lg * 4 + q, 64);  // row's x2 lives at lane la=row%16
            int grow = rowbase + ra * 16 + lg * 4 + q;
            const float* rrow = r + (size_t)grow * M_CLUSTERS;
#pragma unroll
            for (int cb = 0; cb < 4; ++cb)
                rv[ra][q][cb] = (grow < N) ? rrow[cb * 16 + la] : 0.f;
        }

    float partial = 0.f;
#pragma unroll
    for (int ra = 0; ra < 2; ++ra)
#pragma unroll
        for (int q = 0; q < 4; ++q) {
            int grow = rowbase + ra * 16 + lg * 4 + q;
            if (grow < N) {
#pragma unroll
                for (int cb = 0; cb < 4; ++cb) {
                    float sq = x2r[ra][q] + m2r[cb] - 2.0f * acc[ra][cb][q];
                    partial = fmaf(rv[ra][q][cb], zval(sq), partial);
                }
            }
        }

    // Block reduce.
    pl[tid] = partial;
    __syncthreads();
    if (tid < 64) {
        float s = pl[lane] + pl[64 + lane] + pl[128 + lane] + pl[192 + lane];
#pragma unroll
        for (int off = 32; off > 0; off >>= 1)
            s += __shfl_down(s, off, 64);
        if (lane == 0) partials[blockIdx.x] = s;
    }
}

// Deterministic fixed-order final reduction.
__global__ void iso_reduce(const float* __restrict__ partials, int nblocks,
                           float* __restrict__ out, float invN) {
    float s = 0.f;
    for (int i = threadIdx.x; i < nblocks; i += RBLOCK) s += partials[i];
#pragma unroll
    for (int off = 32; off > 0; off >>= 1)
        s += __shfl_down(s, off, 64);
    __shared__ float wsum[RBLOCK / 64];
    const int lane = threadIdx.x & 63;
    const int wid = threadIdx.x >> 6;
    if (lane == 0) wsum[wid] = s;
    __syncthreads();
    if (threadIdx.x == 0)
        out[0] = (wsum[0] + wsum[1] + wsum[2] + wsum[3]) * invN;
}

extern "C" void kernel_launch(void* const* d_in, const int* in_sizes, int n_in,
                              void* d_out, int out_size, void* d_ws, size_t ws_size,
                              hipStream_t stream) {
    const float* X = (const float*)d_in[0];    // [N,128]
    const float* r = (const float*)d_in[1];    // [N,64]
    const float* mus = (const float*)d_in[2];  // [64,128]
    const int N = in_sizes[0] / D_DIM;

    // ws: muB4 (1024 int4 = 16KB) | m2 (64 f32) | partials (nblocks f32)
    int4* muB4 = (int4*)d_ws;
    float* m2 = (float*)((char*)d_ws + 16384);
    float* partials = m2 + M_CLUSTERS;

    const int nblocks = (N + ROWS - 1) / ROWS;

    hipLaunchKernelGGL(iso_prep, dim3(1), dim3(256), 0, stream,
                       (const float4*)mus, muB4, m2);
    hipLaunchKernelGGL(iso_main, dim3(nblocks), dim3(BLOCK), 0, stream,
                       (const float4*)X, r, muB4, m2, partials, N);
    hipLaunchKernelGGL(iso_reduce, dim3(1), dim3(RBLOCK), 0, stream,
                       partials, nblocks, (float*)d_out, 1.0f / (float)N);
}